// Round 12
// baseline (246.394 us; speedup 1.0000x reference)
//
#include <hip/hip_runtime.h>
#include <hip/hip_bf16.h>
#include <math.h>

// Problem constants
#define Bc   2
#define Lc   2048
#define DMc  1536
#define Hc   12
#define FDc  16
#define DVc  128
#define D2c  256
#define CHK  128
#define NCH  16
#define ROWS (Bc*Lc)          // 4096
#define HFD  (Hc*FDc)         // 192
#define HDV  (Hc*DVc)         // 1536
#define NQK  (2*HFD)          // 384 fused q|k projection width
#define NPRJ (NQK + HDV)      // 1920 fused q|k|v projection width

typedef __bf16 bf16x8 __attribute__((ext_vector_type(8)));
typedef float f32x4 __attribute__((ext_vector_type(4)));

__device__ __forceinline__ float bf2f(unsigned short u) {
    return __uint_as_float(((unsigned int)u) << 16);
}
__device__ __forceinline__ unsigned short f2bf(float v) {
    unsigned int u = __float_as_uint(v);
    unsigned int r = (u + 0x7FFFu + ((u >> 16) & 1u)) >> 16;
    return (unsigned short)r;
}
__device__ __forceinline__ unsigned int pack2(unsigned short a, unsigned short b) {
    return (unsigned int)a | ((unsigned int)b << 16);
}
__device__ __forceinline__ float ldin(const void* p, size_t i, int isf32) {
    return isf32 ? ((const float*)p)[i] : bf2f(((const unsigned short*)p)[i]);
}

#define GLL16(g, l) __builtin_amdgcn_global_load_lds( \
    (const __attribute__((address_space(1))) unsigned int*)(g), \
    (__attribute__((address_space(3))) unsigned int*)(l), 16, 0, 0)

// ---------------------------------------------------------------------------
// Dtype probe: writes flag 0 = bf16 data, 1 = f32 data.
// ---------------------------------------------------------------------------
__global__ void probe_dtype(const unsigned short* __restrict__ hs, int* __restrict__ flag) {
    const int tid = threadIdx.x;
    int sane = 0;
    for (int i = tid; i < 1024; i += 256) {
        unsigned short b = hs[2 * i];
        int e = (b >> 7) & 0xFF;
        if (e >= 97 && e <= 157) sane++;
    }
    __shared__ int tot;
    if (tid == 0) tot = 0;
    __syncthreads();
    atomicAdd(&tot, sane);
    __syncthreads();
    if (tid == 0) *flag = (tot >= 614) ? 0 : 1;
}

// ---------------------------------------------------------------------------
// Fused prep kernel (7440 blocks):
//   blocks [0,72):      Wq  -> Wqkvt             (rows=DMc, cols=HFD)
//   blocks [72,144):    Wk  -> Wqkvt + HFD*DMc
//   blocks [144,720):   Wv  -> Wqkvt + NQK*DMc   (rows=DMc, cols=HDV)
//   blocks [720,1296):  Wo  -> Wot               (rows=HDV, cols=DMc)
//   blocks [1296,7440): elementwise hs -> hsb bf16 (4 elems/thread)
// Wt[n][k] = bf16(W[k][n]).
// ---------------------------------------------------------------------------
__global__ __launch_bounds__(256) void prep_all(const void* __restrict__ hs,
                                                const void* __restrict__ Wq,
                                                const void* __restrict__ Wk,
                                                const void* __restrict__ Wv,
                                                const void* __restrict__ Wo,
                                                unsigned short* __restrict__ hsb,
                                                unsigned short* __restrict__ Wqkvt,
                                                unsigned short* __restrict__ Wot,
                                                const int* __restrict__ flagp) {
    const int f = *flagp;
    const int t = threadIdx.x;
    int id = blockIdx.x;
    if (id >= 1296) {
        const int n4 = ROWS * DMc / 4;
        int i = (id - 1296) * 256 + t;
        if (i < n4) {
            if (f) {
                float4 x = ((const float4*)hs)[i];
                ushort4 y;
                y.x = f2bf(x.x); y.y = f2bf(x.y); y.z = f2bf(x.z); y.w = f2bf(x.w);
                ((ushort4*)hsb)[i] = y;
            } else {
                ((ushort4*)hsb)[i] = ((const ushort4*)hs)[i];
            }
        }
        return;
    }
    __shared__ float tile[64][65];
    const void* W; unsigned short* Wt; int rows, cols, bx, by;
    if (id < 72)       { W = Wq; Wt = Wqkvt;                          rows = DMc; cols = HFD; bx = (id % 3) * 64;  by = (id / 3) * 64; }
    else if (id < 144) { id -= 72;  W = Wk; Wt = Wqkvt + (size_t)HFD * DMc; rows = DMc; cols = HFD; bx = (id % 3) * 64;  by = (id / 3) * 64; }
    else if (id < 720) { id -= 144; W = Wv; Wt = Wqkvt + (size_t)NQK * DMc; rows = DMc; cols = HDV; bx = (id % 24) * 64; by = (id / 24) * 64; }
    else               { id -= 720; W = Wo; Wt = Wot;                 rows = HDV; cols = DMc; bx = (id % 24) * 64; by = (id / 24) * 64; }
#pragma unroll
    for (int u = 0; u < 16; u++) {
        int idx = t + u * 256;
        int r = idx >> 6, c = idx & 63;
        tile[r][c] = ldin(W, (size_t)(by + r) * cols + bx + c, f);
    }
    __syncthreads();
#pragma unroll
    for (int u = 0; u < 16; u++) {
        int idx = t + u * 256;
        int r = idx >> 6, c = idx & 63;
        Wt[(size_t)(bx + r) * rows + by + c] = f2bf(tile[c][r]);
    }
}

// ---------------------------------------------------------------------------
// MFMA bf16 GEMM: C(MxN) = A(MxK) @ Bt(NxK)^T. 128x128 tile, 8 waves with
// in-block split-K: waves 0-3 accumulate K[0, K/2), waves 4-7 K[K/2, K);
// accumulators merged through LDS at the end (two 32 KB rounds).
// XCD-chunked block swizzle (bijective since nwg%8==0).
// cMode: 0 = C f32, 1 = C bf16, 2 = flagged, 3 = no C (vTout only),
//        4 = fused proj (col<NQK -> C f32 with stride ldc; else vT bf16).
// ---------------------------------------------------------------------------
__global__ __launch_bounds__(512) void gemm_mfma_bt(const unsigned short* __restrict__ A,
                                                    const unsigned short* __restrict__ Bt,
                                                    void* __restrict__ C,
                                                    int M, int N, int K,
                                                    int ldc,
                                                    int cMode, const int* __restrict__ flagp,
                                                    unsigned short* __restrict__ vTout) {
    const int f = *flagp;
    __shared__ __align__(16) unsigned char smem[32768];
    unsigned short* As = (unsigned short*)smem;      // [2][128][32] bf16 16 KB
    unsigned short* Bsu = As + 8192;                 // [2][128][32] bf16 16 KB
    f32x4* scr4 = (f32x4*)smem;                      // merge scratch (32 KB)

    const int tid = threadIdx.x;
    const int wave = tid >> 6, lane = tid & 63;
    const int kgrp = wave >> 2;          // 0 or 1: K-half
    const int w4 = wave & 3;             // spatial wave id within group
    const int lin = blockIdx.y * gridDim.x + blockIdx.x;
    const int nwg = gridDim.x * gridDim.y;
    const int swz = (lin & 7) * (nwg >> 3) + (lin >> 3);
    const int row0 = (swz / gridDim.x) * 128, col0 = (swz % gridDim.x) * 128;
    const int wrow = (w4 >> 1) * 64, wcol = (w4 & 1) * 64;
    const int mlane = lane & 15, quad = lane >> 4;
    const int kHalf = K >> 1;

    const unsigned short* Ab = A + (size_t)row0 * K + (size_t)kgrp * kHalf;
    const unsigned short* Bb = Bt + (size_t)col0 * K + (size_t)kgrp * kHalf;
    const int t256 = tid & 255;
    const int r0 = t256 >> 2;
    const int kc = (t256 & 3) * 8;
    const size_t off0 = (size_t)r0 * K + kc;
    const size_t off1 = (size_t)(r0 + 64) * K + kc;
    char* AsW = (char*)As + kgrp * 8192 + w4 * 1024;
    char* BsW = (char*)Bsu + kgrp * 8192 + w4 * 1024;
    const int ldsBase = kgrp * 4096;

    f32x4 acc[4][4] = {};

    for (int k0 = 0; k0 < kHalf; k0 += 32) {
        GLL16(Ab + off0 + k0, AsW);
        GLL16(Ab + off1 + k0, AsW + 4096);
        GLL16(Bb + off0 + k0, BsW);
        GLL16(Bb + off1 + k0, BsW + 4096);
        __syncthreads();
        bf16x8 a[4], b[4];
#pragma unroll
        for (int i = 0; i < 4; i++)
            a[i] = *(const bf16x8*)&As[ldsBase + (wrow + i * 16 + mlane) * 32 + quad * 8];
#pragma unroll
        for (int j = 0; j < 4; j++)
            b[j] = *(const bf16x8*)&Bsu[ldsBase + (wcol + j * 16 + mlane) * 32 + quad * 8];
#pragma unroll
        for (int i = 0; i < 4; i++)
#pragma unroll
            for (int j = 0; j < 4; j++)
                acc[i][j] = __builtin_amdgcn_mfma_f32_16x16x32_bf16(a[i], b[j], acc[i][j], 0, 0, 0);
        __syncthreads();
    }

    // --- accumulator merge: waves 4..7 hand their acc to waves 0..3 ---
    {
        const int col = (wave & 1) * 64 + lane;
        if (kgrp == 1 && w4 < 2) {
#pragma unroll
            for (int i = 0; i < 4; i++)
#pragma unroll
                for (int j = 0; j < 4; j++)
                    scr4[(i * 4 + j) * 128 + col] = acc[i][j];
        }
        __syncthreads();
        if (kgrp == 0 && w4 < 2) {
#pragma unroll
            for (int i = 0; i < 4; i++)
#pragma unroll
                for (int j = 0; j < 4; j++)
                    acc[i][j] += scr4[(i * 4 + j) * 128 + col];
        }
        __syncthreads();
        if (kgrp == 1 && w4 >= 2) {
#pragma unroll
            for (int i = 0; i < 4; i++)
#pragma unroll
                for (int j = 0; j < 4; j++)
                    scr4[(i * 4 + j) * 128 + col] = acc[i][j];
        }
        __syncthreads();
        if (kgrp == 0 && w4 >= 2) {
#pragma unroll
            for (int i = 0; i < 4; i++)
#pragma unroll
                for (int j = 0; j < 4; j++)
                    acc[i][j] += scr4[(i * 4 + j) * 128 + col];
        }
    }
    if (kgrp != 0) return;

    // --- epilogue routing ---
    float* Cf = nullptr;
    unsigned short* Cb16 = nullptr;
    bool doT = false;
    int tOff = 0;
    if (cMode == 0) Cf = (float*)C;
    else if (cMode == 1) Cb16 = (unsigned short*)C;
    else if (cMode == 2) { if (f) Cf = (float*)C; else Cb16 = (unsigned short*)C; }
    else if (cMode == 4) {
        if (col0 < NQK) Cf = (float*)C;
        else { doT = true; tOff = NQK; }
    }
    if (cMode <= 3 && vTout) doT = true;

#pragma unroll
    for (int i = 0; i < 4; i++)
#pragma unroll
        for (int j = 0; j < 4; j++) {
            const int col = col0 + wcol + j * 16 + mlane;
            if (Cf) {
#pragma unroll
                for (int r = 0; r < 4; r++) {
                    const int row = row0 + wrow + i * 16 + quad * 4 + r;
                    Cf[(size_t)row * ldc + col] = acc[i][j][r];
                }
            } else if (Cb16) {
#pragma unroll
                for (int r = 0; r < 4; r++) {
                    const int row = row0 + wrow + i * 16 + quad * 4 + r;
                    Cb16[(size_t)row * ldc + col] = f2bf(acc[i][j][r]);
                }
            }
            if (doT) {
                ushort4 pk;
                pk.x = f2bf(acc[i][j][0]); pk.y = f2bf(acc[i][j][1]);
                pk.z = f2bf(acc[i][j][2]); pk.w = f2bf(acc[i][j][3]);
                *(ushort4*)(vTout + (size_t)(col - tOff) * M + row0 + wrow + i * 16 + quad * 4) = pk;
            }
        }
}

// ---------------------------------------------------------------------------
// Fused LayerNorm: reads fused qk (4096 x 384), writes qpre/kpre (4096 x 192).
// ---------------------------------------------------------------------------
__global__ __launch_bounds__(192) void ln_kernel(const float* __restrict__ qk,
                                                 float* __restrict__ q, float* __restrict__ k,
                                                 const void* __restrict__ gq,
                                                 const void* __restrict__ bq,
                                                 const void* __restrict__ gk,
                                                 const void* __restrict__ bk,
                                                 const int* __restrict__ flagp) {
    const int f = *flagp;
    const int row = blockIdx.x, t = threadIdx.x;
    float vq = qk[(size_t)row * NQK + t];
    float vk = qk[(size_t)row * NQK + HFD + t];
    float s[4] = {vq, vq * vq, vk, vk * vk};
    __shared__ float part[4][3];
    const int w = t >> 6, lane = t & 63;
#pragma unroll
    for (int i = 0; i < 4; i++) {
        float v = s[i];
        for (int off = 32; off; off >>= 1) v += __shfl_down(v, off);
        if (lane == 0) part[i][w] = v;
    }
    __syncthreads();
    float sq  = part[0][0] + part[0][1] + part[0][2];
    float sq2 = part[1][0] + part[1][1] + part[1][2];
    float sk  = part[2][0] + part[2][1] + part[2][2];
    float sk2 = part[3][0] + part[3][1] + part[3][2];
    const float inv = 1.0f / (float)HFD;
    float muq = sq * inv, muk = sk * inv;
    float varq = sq2 * inv - muq * muq;
    float vark = sk2 * inv - muk * muk;
    float oq = (vq - muq) * rsqrtf(varq + 1e-5f) * ldin(gq, t, f) + ldin(bq, t, f);
    float ok = (vk - muk) * rsqrtf(vark + 1e-5f) * ldin(gk, t, f) + ldin(bk, t, f);
    q[(size_t)row * HFD + t] = oq;
    k[(size_t)row * HFD + t] = ok;
}

// ---------------------------------------------------------------------------
// Fused chunk-state + exclusive prefix + z prefix, MFMA.
// 1-D grid 768, XCD-chunk-swizzled.
// ---------------------------------------------------------------------------
__global__ __launch_bounds__(256) void state_prefix_mfma(const float* __restrict__ kn,
                                                         const unsigned short* __restrict__ vT,
                                                         unsigned short* __restrict__ St,
                                                         float* __restrict__ zc) {
    const int lin = blockIdx.x;
    const int swz = (lin & 7) * 96 + (lin >> 3);   // 768 % 8 == 0, bijective
    const int bx = swz & 15;            // d2 tile = i index
    const int by = (swz >> 4) & 1;      // dv half
    const int bh = swz >> 5;
    const int h = bh % Hc, b = bh / Hc;
    const int t0 = bx * 16;
    const int tid = threadIdx.x;
    const int wave = tid >> 6, lane = tid & 63;
    const int mlane = lane & 15, quad = lane >> 4;

    __shared__ __align__(16) float kcs[CHK * FDc];          // [c][16] f32, 8 KB
    __shared__ __align__(16) unsigned short K2t[16 * 136];  // [d2l][c pad]  4.25 KB
    __shared__ __align__(16) unsigned short Vs[64 * 136];   // [dvL][c pad] 17 KB
    __shared__ float zp[16][17];
    __shared__ float zpre[16];
    if (tid < 16) zpre[tid] = 0.f;

    f32x4 acc = {};
    const int kr = tid >> 1, khf = tid & 1;
    const int d2l = tid & 15, cg = tid >> 4;
    const int vrow = tid >> 2, vseg = tid & 3;
    const int dvL = wave * 16 + mlane;

    for (int n = 0; n < NCH; n++) {
        const int row0 = b * Lc + n * CHK;
        __syncthreads();
        {
            const float4* src = (const float4*)(kn + (size_t)(row0 + kr) * HFD + h * FDc + khf * 8);
            *(float4*)(kcs + kr * 16 + khf * 8)     = src[0];
            *(float4*)(kcs + kr * 16 + khf * 8 + 4) = src[1];
            const uint4* g = (const uint4*)(vT + (size_t)(h * 128 + by * 64 + vrow) * ROWS + row0 + vseg * 32);
            *(uint4*)(Vs + vrow * 136 + vseg * 32)      = g[0];
            *(uint4*)(Vs + vrow * 136 + vseg * 32 + 8)  = g[1];
            *(uint4*)(Vs + vrow * 136 + vseg * 32 + 16) = g[2];
            *(uint4*)(Vs + vrow * 136 + vseg * 32 + 24) = g[3];
        }
        __syncthreads();
        {
            float zs_ = 0.f;
            unsigned short pk[8];
#pragma unroll
            for (int u = 0; u < 8; u++) {
                int c = cg * 8 + u;
                float p = kcs[c * 16 + bx] * kcs[c * 16 + d2l] * 0.25f;
                zs_ += p;
                pk[u] = f2bf(p);
            }
            uint4 w;
            w.x = pack2(pk[0], pk[1]); w.y = pack2(pk[2], pk[3]);
            w.z = pack2(pk[4], pk[5]); w.w = pack2(pk[6], pk[7]);
            *(uint4*)(K2t + d2l * 136 + cg * 8) = w;
            zp[d2l][cg] = zs_;
        }
        __syncthreads();
        {
            size_t base = (((size_t)(bh * NCH + n) * 16 + bx) * 128) * 16;
            int dv = by * 64 + dvL;
            ushort4 pk;
            pk.x = f2bf(acc[0]); pk.y = f2bf(acc[1]);
            pk.z = f2bf(acc[2]); pk.w = f2bf(acc[3]);
            *(ushort4*)(St + base + (size_t)dv * 16 + quad * 4) = pk;
            if (tid < 16) {
                float s = 0.f;
#pragma unroll
                for (int c = 0; c < 16; c++) s += zp[tid][c];
                if (by == 0)
                    zc[(size_t)(bh * NCH + n) * D2c + t0 + tid] = zpre[tid];
                zpre[tid] += s;
            }
        }
        {
#pragma unroll
            for (int ks = 0; ks < 4; ks++) {
                bf16x8 a = *(const bf16x8*)(K2t + mlane * 136 + ks * 32 + quad * 8);
                bf16x8 bfr = *(const bf16x8*)(Vs + dvL * 136 + ks * 32 + quad * 8);
                acc = __builtin_amdgcn_mfma_f32_16x16x32_bf16(a, bfr, acc, 0, 0, 0);
            }
        }
    }
}

// ---------------------------------------------------------------------------
// MFMA chunk output, 8-wave in-block split (XCD-chunk-swizzled grid 384):
//   waves 0-3 (kgrp0): num1 d2 in [0,128), num2 e in [0,64)
//   waves 4-7 (kgrp1): num1 d2 in [128,256), num2 e in [64,128)
//   P = Q @ K^T split 8 ways (64x32 piece per wave)
//   accumulators merged once through LDS at the end (GEMM merge pattern).
// LDS phase-aliased (60928 B): see offsets below; all row strides 16B-mult.
// ---------------------------------------------------------------------------
__global__ __launch_bounds__(512) void chunk_out_mfma(const float* __restrict__ qn,
                                                      const float* __restrict__ kn,
                                                      const unsigned short* __restrict__ St,
                                                      const float* __restrict__ z,
                                                      const unsigned short* __restrict__ vT,
                                                      unsigned short* __restrict__ o) {
    const int lin = blockIdx.x;
    const int blk = (lin & 7) * 48 + (lin >> 3);   // 384 % 8 == 0, bijective
    const int n = blk & 15, bh = blk >> 4;
    const int h = bh % Hc, b = bh / Hc;
    const int row0 = b * Lc + n * CHK;
    const int tid = threadIdx.x;
    const int wave = tid >> 6, lane = tid & 63;
    const int kgrp = wave >> 2, w4 = wave & 3;
    const int t256 = tid & 255;
    const int mlane = lane & 15, quad = lane >> 4;
    const int wrow = (w4 >> 1) * 64, wcol = (w4 & 1) * 64;

    __shared__ __align__(16) unsigned char lds[60928];
    float* zs   = (float*)lds;                            // [256]        1024
    float* denp = (float*)(lds + 1024);                   // [4][128]     2048
    float* dinv = (float*)(lds + 3072);                   // [128]         512
    unsigned short* Qb  = (unsigned short*)(lds + 3584);  // [128][32]    8192
    unsigned short* Kb  = (unsigned short*)(lds + 11776); // [128][32]    8192
    float* Qs   = (float*)(lds + 19968);                  // [128][16]    8192 (dead after Qb build)
    unsigned short* Q2s = (unsigned short*)(lds + 19968); // [2][128][40] 20480 (num1; aliases dead Qs)
    unsigned short* Sts = (unsigned short*)(lds + 40448); // [2][128][40] 20480 (num1)
    unsigned short* At  = (unsigned short*)(lds + 22016); // [128][136]   34816 (P..num2; aliases dead Q2s/Sts)
    unsigned short* Vs1 = (unsigned short*)(lds + 3584);  // [128][72]    18432 (num2; aliases dead Qb/Kb)
    f32x4* scr4 = (f32x4*)(lds + 3584);                   // merge scratch 32768 (aliases dead Vs1/At)

    // ---- phase 0: load Qs (f32) + zs ----
    {
        int r = tid >> 2, q4 = tid & 3;
        const float4* src = (const float4*)(qn + (size_t)(row0 + r) * HFD + h * FDc + q4 * 4);
        *(float4*)(Qs + r * 16 + q4 * 4) = src[0];
        if (tid < 64)
            ((float4*)zs)[tid] = ((const float4*)(z + ((size_t)bh * NCH + n) * D2c))[tid];
    }
    __syncthreads();

    const int qc = t256 >> 1, qhalf = t256 & 1;
    float qr[16];
#pragma unroll
    for (int ff = 0; ff < 16; ff++) qr[ff] = Qs[qc * 16 + ff];

    // ---- phase 0.5: build Qb, Kb zero-padded [128][32] (Qs dies here) ----
    {
        int r = tid >> 2, q4 = tid & 3;
        uint4 zz = make_uint4(0, 0, 0, 0);
        unsigned short p8[8];
        if (q4 < 2) {
#pragma unroll
            for (int ff = 0; ff < 8; ff++) p8[ff] = f2bf(Qs[r * 16 + q4 * 8 + ff]);
            uint4 w;
            w.x = pack2(p8[0], p8[1]); w.y = pack2(p8[2], p8[3]);
            w.z = pack2(p8[4], p8[5]); w.w = pack2(p8[6], p8[7]);
            *(uint4*)(Qb + r * 32 + q4 * 8) = w;
            *(uint4*)(Qb + r * 32 + 16 + q4 * 8) = zz;
        } else {
            const float* kg = kn + (size_t)(row0 + r) * HFD + h * FDc + (q4 - 2) * 8;
#pragma unroll
            for (int ff = 0; ff < 8; ff++) p8[ff] = f2bf(kg[ff]);
            uint4 w;
            w.x = pack2(p8[0], p8[1]); w.y = pack2(p8[2], p8[3]);
            w.z = pack2(p8[4], p8[5]); w.w = pack2(p8[6], p8[7]);
            *(uint4*)(Kb + r * 32 + (q4 - 2) * 8) = w;
            *(uint4*)(Kb + r * 32 + 16 + (q4 - 2) * 8) = zz;
        }
    }
    __syncthreads();

    f32x4 acc[4][4] = {};
    float den1 = 0.f;
    const unsigned short* Stb = St + ((size_t)bh * NCH + n) * ((size_t)D2c * DVc);
    unsigned short* Q2g = Q2s + kgrp * (128 * 40);
    unsigned short* Stg = Sts + kgrp * (128 * 40);

    // ---- num1: per kgrp 4 slabs over its d2-half ----
    for (int s = 0; s < 4; s++) {
        const int k0 = kgrp * 128 + s * 32;
        {
            unsigned short pk[16];
#pragma unroll
            for (int kk = 0; kk < 16; kk++) {
                int d2 = k0 + qhalf * 16 + kk;
                float val = qr[d2 >> 4] * qr[d2 & 15] * 0.25f;
                den1 += val * zs[d2];
                pk[kk] = f2bf(val);
            }
            uint4 w0, w1;
            w0.x = pack2(pk[0], pk[1]);  w0.y = pack2(pk[2], pk[3]);
            w0.z = pack2(pk[4], pk[5]);  w0.w = pack2(pk[6], pk[7]);
            w1.x = pack2(pk[8], pk[9]);  w1.y = pack2(pk[10], pk[11]);
            w1.z = pack2(pk[12], pk[13]); w1.w = pack2(pk[14], pk[15]);
            *(uint4*)(Q2g + qc * 40 + qhalf * 16) = w0;
            *(uint4*)(Q2g + qc * 40 + qhalf * 16 + 8) = w1;
        }
        {
            // St tile-major: element (dv=r, d2=k0+hf*16+s16) at (k0/16+hf)*2048 + r*16 + s16
            const uint4* g = (const uint4*)(Stb + (size_t)((k0 >> 4) + qhalf) * 2048 + qc * 16);
            uint4 d0 = g[0], d1 = g[1];
            *(uint4*)(Stg + qc * 40 + qhalf * 16) = d0;
            *(uint4*)(Stg + qc * 40 + qhalf * 16 + 8) = d1;
        }
        __syncthreads();
        bf16x8 a[4], bfr[4];
#pragma unroll
        for (int i = 0; i < 4; i++)
            a[i] = *(const bf16x8*)(Q2g + (wrow + i * 16 + mlane) * 40 + quad * 8);
#pragma unroll
        for (int j = 0; j < 4; j++)
            bfr[j] = *(const bf16x8*)(Stg + (wcol + j * 16 + mlane) * 40 + quad * 8);
#pragma unroll
        for (int i = 0; i < 4; i++)
#pragma unroll
            for (int j = 0; j < 4; j++)
                acc[i][j] = __builtin_amdgcn_mfma_f32_16x16x32_bf16(a[i], bfr[j], acc[i][j], 0, 0, 0);
        __syncthreads();
    }
    denp[(kgrp * 2 + qhalf) * 128 + qc] = den1;

    // ---- P = Q @ K^T, A = tril(P^2/16); 8 waves, 64x32 piece each ----
    {
        const int rowblk = wave >> 2, colblk = wave & 3;
        f32x4 pacc[4][2] = {};
        bf16x8 a[4], bfr[2];
#pragma unroll
        for (int i = 0; i < 4; i++)
            a[i] = *(const bf16x8*)(Qb + (rowblk * 64 + i * 16 + mlane) * 32 + quad * 8);
#pragma unroll
        for (int j = 0; j < 2; j++)
            bfr[j] = *(const bf16x8*)(Kb + (colblk * 32 + j * 16 + mlane) * 32 + quad * 8);
#pragma unroll
        for (int i = 0; i < 4; i++)
#pragma unroll
            for (int j = 0; j < 2; j++)
                pacc[i][j] = __builtin_amdgcn_mfma_f32_16x16x32_bf16(a[i], bfr[j], pacc[i][j], 0, 0, 0);
#pragma unroll
        for (int i = 0; i < 4; i++)
#pragma unroll
            for (int j = 0; j < 2; j++) {
                int e = colblk * 32 + j * 16 + mlane;
#pragma unroll
                for (int r = 0; r < 4; r++) {
                    int c = rowblk * 64 + i * 16 + quad * 4 + r;
                    float p = pacc[i][j][r];
                    float aval = (e <= c) ? p * p * 0.0625f : 0.f;
                    At[c * 136 + e] = f2bf(aval);
                }
            }
    }
    __syncthreads();

    // ---- dinv[c] = 1/(den1 + rowsum(A) + eps) ----
    if (tid < 128) {
        float rs = 0.f;
#pragma unroll
        for (int e8 = 0; e8 < 128; e8 += 8) {
            bf16x8 v8 = *(const bf16x8*)(At + tid * 136 + e8);
#pragma unroll
            for (int u = 0; u < 8; u++) rs += (float)v8[u];
        }
        dinv[tid] = 1.0f / (denp[tid] + denp[128 + tid] + denp[256 + tid] + denp[384 + tid] + rs + 1e-12f);
    }

    // ---- num2: per kgrp 2 slabs over its e-half ----
    for (int s2 = 0; s2 < 2; s2++) {
        const int e0 = kgrp * 64 + s2 * 32;
        {
            const uint4* g = (const uint4*)(vT + (size_t)(h * 128 + qc) * ROWS + row0 + e0 + qhalf * 16);
            uint4 d0 = g[0], d1 = g[1];
            *(uint4*)(Vs1 + qc * 72 + kgrp * 32 + qhalf * 16) = d0;
            *(uint4*)(Vs1 + qc * 72 + kgrp * 32 + qhalf * 16 + 8) = d1;
        }
        __syncthreads();
        bf16x8 a[4], bfr[4];
#pragma unroll
        for (int i = 0; i < 4; i++)
            a[i] = *(const bf16x8*)(At + (wrow + i * 16 + mlane) * 136 + e0 + quad * 8);
#pragma unroll
        for (int j = 0; j < 4; j++)
            bfr[j] = *(const bf16x8*)(Vs1 + (wcol + j * 16 + mlane) * 72 + kgrp * 32 + quad * 8);
#pragma unroll
        for (int i = 0; i < 4; i++)
#pragma unroll
            for (int j = 0; j < 4; j++)
                acc[i][j] = __builtin_amdgcn_mfma_f32_16x16x32_bf16(a[i], bfr[j], acc[i][j], 0, 0, 0);
        __syncthreads();
    }

    // ---- accumulator merge: kgrp1 -> kgrp0 (GEMM pattern) ----
    {
        const int col = (w4 & 1) * 64 + lane;
        if (kgrp == 1 && w4 < 2) {
#pragma unroll
            for (int i = 0; i < 4; i++)
#pragma unroll
                for (int j = 0; j < 4; j++)
                    scr4[(i * 4 + j) * 128 + col] = acc[i][j];
        }
        __syncthreads();
        if (kgrp == 0 && w4 < 2) {
#pragma unroll
            for (int i = 0; i < 4; i++)
#pragma unroll
                for (int j = 0; j < 4; j++)
                    acc[i][j] += scr4[(i * 4 + j) * 128 + col];
        }
        __syncthreads();
        if (kgrp == 1 && w4 >= 2) {
#pragma unroll
            for (int i = 0; i < 4; i++)
#pragma unroll
                for (int j = 0; j < 4; j++)
                    scr4[(i * 4 + j) * 128 + col] = acc[i][j];
        }
        __syncthreads();
        if (kgrp == 0 && w4 >= 2) {
#pragma unroll
            for (int i = 0; i < 4; i++)
#pragma unroll
                for (int j = 0; j < 4; j++)
                    acc[i][j] += scr4[(i * 4 + j) * 128 + col];
        }
    }
    if (kgrp != 0) return;

    // ---- epilogue (waves 0-3) ----
#pragma unroll
    for (int i = 0; i < 4; i++)
#pragma unroll
        for (int j = 0; j < 4; j++) {
            int col = h * 128 + wcol + j * 16 + mlane;
#pragma unroll
            for (int r = 0; r < 4; r++) {
                int c = wrow + i * 16 + quad * 4 + r;
                o[(size_t)(row0 + c) * HDV + col] = f2bf(acc[i][j][r] * dinv[c]);
            }
        }
}

// ---------------------------------------------------------------------------
extern "C" void kernel_launch(void* const* d_in, const int* in_sizes, int n_in,
                              void* d_out, int out_size, void* d_ws, size_t ws_size,
                              hipStream_t stream) {
    const void* hs = d_in[0];
    const void* Wq = d_in[1];
    const void* Wk = d_in[2];
    const void* Wv = d_in[3];
    const void* Wo = d_in[4];
    const void* gq = d_in[5];
    const void* bq = d_in[6];
    const void* gk = d_in[7];
    const void* bk = d_in[8];

    int* flag = (int*)d_ws;
    float* base = (float*)d_ws + 16;
    float* qpre = base;                                   // 4096*192 f32
    float* kpre = qpre + (size_t)ROWS * HFD;              // 4096*192 f32
    float* vreg = kpre + (size_t)ROWS * HFD;              // 25.2 MB region (St lives here)
    float* Sc   = vreg + (size_t)ROWS * HDV;              // 50 MB region (qk/Wqkvt aliases)
    float* zc   = Sc + (size_t)Bc * Hc * NCH * D2c * DVc; // 384*256 f32
    float* fend = zc + (size_t)Bc * Hc * NCH * D2c;
    unsigned short* hsb = (unsigned short*)fend;          // 4096*1536 bf16
    unsigned short* ob  = hsb;                            // alias (hsb dead before ob)
    unsigned short* Wot = hsb + (size_t)ROWS * DMc;       // 1536*1536 bf16
    unsigned short* vT  = Wot + (size_t)HDV * DMc;        // 1536*4096 bf16 (12.6 MB)
    // aliases into Sc region:
    float* qk = Sc;                                       // 4096*384 f32 (dead after ln)
    unsigned short* Wqkvt = (unsigned short*)(Sc + (size_t)ROWS * NQK);  // 1920*1536 bf16 (dead after proj)
    // St (bf16 exclusive-prefix state, tile-major) uses the old v region.
    unsigned short* St = (unsigned short*)vreg;           // 24*16*16*128*16 bf16 = 25.2 MB

    probe_dtype<<<1, 256, 0, stream>>>((const unsigned short*)hs, flag);

    // fused bf16 prep: weight transposes + hs conversion in one launch
    prep_all<<<1296 + ROWS * DMc / 1024, 256, 0, stream>>>(
        hs, Wq, Wk, Wv, Wo, hsb, Wqkvt, Wot, flag);

    // fused projection: [qk | v] = hs @ [Wq|Wk|Wv]; qk cols -> f32 (ldc=NQK),
    // v cols -> vT bf16 transposed. 480 blocks x 8 waves, split-K, XCD-swizzled.
    gemm_mfma_bt<<<dim3(NPRJ / 128, ROWS / 128), 512, 0, stream>>>(
        hsb, Wqkvt, qk, ROWS, NPRJ, DMc, NQK, 4, flag, vT);

    ln_kernel<<<ROWS, HFD, 0, stream>>>(qk, qpre, kpre, gq, bq, gk, bk, flag);

    // fused state + prefix (1-D grid, XCD-chunk-swizzled)
    state_prefix_mfma<<<16 * 2 * Bc * Hc, 256, 0, stream>>>(kpre, vT, St, zc);

    // chunk output (8-wave split, XCD-chunk-swizzled)
    chunk_out_mfma<<<Bc * Hc * NCH, 512, 0, stream>>>(qpre, kpre, St, zc, vT, ob);

    // out = o @ Wo, direct write (384 blocks x 8 waves, split-K, XCD-swizzled)
    gemm_mfma_bt<<<dim3(DMc / 128, ROWS / 128), 512, 0, stream>>>(
        ob, Wot, d_out, ROWS, DMc, HDV, DMc, 2, flag, nullptr);
}

// Round 13
// 235.355 us; speedup vs baseline: 1.0469x; 1.0469x over previous
//
#include <hip/hip_runtime.h>
#include <hip/hip_bf16.h>
#include <math.h>

// Problem constants
#define Bc   2
#define Lc   2048
#define DMc  1536
#define Hc   12
#define FDc  16
#define DVc  128
#define D2c  256
#define CHK  128
#define NCH  16
#define ROWS (Bc*Lc)          // 4096
#define HFD  (Hc*FDc)         // 192
#define HDV  (Hc*DVc)         // 1536
#define NQK  (2*HFD)          // 384 fused q|k projection width
#define NPRJ (NQK + HDV)      // 1920 fused q|k|v projection width

typedef __bf16 bf16x8 __attribute__((ext_vector_type(8)));
typedef float f32x4 __attribute__((ext_vector_type(4)));

__device__ __forceinline__ float bf2f(unsigned short u) {
    return __uint_as_float(((unsigned int)u) << 16);
}
__device__ __forceinline__ unsigned short f2bf(float v) {
    unsigned int u = __float_as_uint(v);
    unsigned int r = (u + 0x7FFFu + ((u >> 16) & 1u)) >> 16;
    return (unsigned short)r;
}
__device__ __forceinline__ unsigned int pack2(unsigned short a, unsigned short b) {
    return (unsigned int)a | ((unsigned int)b << 16);
}
__device__ __forceinline__ float ldin(const void* p, size_t i, int isf32) {
    return isf32 ? ((const float*)p)[i] : bf2f(((const unsigned short*)p)[i]);
}

#define GLL16(g, l) __builtin_amdgcn_global_load_lds( \
    (const __attribute__((address_space(1))) unsigned int*)(g), \
    (__attribute__((address_space(3))) unsigned int*)(l), 16, 0, 0)

// ---------------------------------------------------------------------------
// Dtype probe: writes flag 0 = bf16 data, 1 = f32 data.
// ---------------------------------------------------------------------------
__global__ void probe_dtype(const unsigned short* __restrict__ hs, int* __restrict__ flag) {
    const int tid = threadIdx.x;
    int sane = 0;
    for (int i = tid; i < 1024; i += 256) {
        unsigned short b = hs[2 * i];
        int e = (b >> 7) & 0xFF;
        if (e >= 97 && e <= 157) sane++;
    }
    __shared__ int tot;
    if (tid == 0) tot = 0;
    __syncthreads();
    atomicAdd(&tot, sane);
    __syncthreads();
    if (tid == 0) *flag = (tot >= 614) ? 0 : 1;
}

// ---------------------------------------------------------------------------
// Fused prep kernel (7440 blocks):
//   blocks [0,72):      Wq  -> Wqkvt             (rows=DMc, cols=HFD)
//   blocks [72,144):    Wk  -> Wqkvt + HFD*DMc
//   blocks [144,720):   Wv  -> Wqkvt + NQK*DMc   (rows=DMc, cols=HDV)
//   blocks [720,1296):  Wo  -> Wot               (rows=HDV, cols=DMc)
//   blocks [1296,7440): elementwise hs -> hsb bf16 (4 elems/thread)
// Wt[n][k] = bf16(W[k][n]).
// ---------------------------------------------------------------------------
__global__ __launch_bounds__(256) void prep_all(const void* __restrict__ hs,
                                                const void* __restrict__ Wq,
                                                const void* __restrict__ Wk,
                                                const void* __restrict__ Wv,
                                                const void* __restrict__ Wo,
                                                unsigned short* __restrict__ hsb,
                                                unsigned short* __restrict__ Wqkvt,
                                                unsigned short* __restrict__ Wot,
                                                const int* __restrict__ flagp) {
    const int f = *flagp;
    const int t = threadIdx.x;
    int id = blockIdx.x;
    if (id >= 1296) {
        const int n4 = ROWS * DMc / 4;
        int i = (id - 1296) * 256 + t;
        if (i < n4) {
            if (f) {
                float4 x = ((const float4*)hs)[i];
                ushort4 y;
                y.x = f2bf(x.x); y.y = f2bf(x.y); y.z = f2bf(x.z); y.w = f2bf(x.w);
                ((ushort4*)hsb)[i] = y;
            } else {
                ((ushort4*)hsb)[i] = ((const ushort4*)hs)[i];
            }
        }
        return;
    }
    __shared__ float tile[64][65];
    const void* W; unsigned short* Wt; int rows, cols, bx, by;
    if (id < 72)       { W = Wq; Wt = Wqkvt;                          rows = DMc; cols = HFD; bx = (id % 3) * 64;  by = (id / 3) * 64; }
    else if (id < 144) { id -= 72;  W = Wk; Wt = Wqkvt + (size_t)HFD * DMc; rows = DMc; cols = HFD; bx = (id % 3) * 64;  by = (id / 3) * 64; }
    else if (id < 720) { id -= 144; W = Wv; Wt = Wqkvt + (size_t)NQK * DMc; rows = DMc; cols = HDV; bx = (id % 24) * 64; by = (id / 24) * 64; }
    else               { id -= 720; W = Wo; Wt = Wot;                 rows = HDV; cols = DMc; bx = (id % 24) * 64; by = (id / 24) * 64; }
#pragma unroll
    for (int u = 0; u < 16; u++) {
        int idx = t + u * 256;
        int r = idx >> 6, c = idx & 63;
        tile[r][c] = ldin(W, (size_t)(by + r) * cols + bx + c, f);
    }
    __syncthreads();
#pragma unroll
    for (int u = 0; u < 16; u++) {
        int idx = t + u * 256;
        int r = idx >> 6, c = idx & 63;
        Wt[(size_t)(bx + r) * rows + by + c] = f2bf(tile[c][r]);
    }
}

// ---------------------------------------------------------------------------
// MFMA bf16 GEMM: C(MxN) = A(MxK) @ Bt(NxK)^T. 128x128 tile, 8 waves with
// in-block split-K: waves 0-3 accumulate K[0, K/2), waves 4-7 K[K/2, K);
// accumulators merged through LDS at the end (two 32 KB rounds).
// XCD-chunked block swizzle (bijective since nwg%8==0).
// cMode: 0 = C f32, 1 = C bf16, 2 = flagged, 3 = no C (vTout only),
//        4 = fused proj (col<NQK -> C f32 with stride ldc; else vT bf16).
// ---------------------------------------------------------------------------
__global__ __launch_bounds__(512) void gemm_mfma_bt(const unsigned short* __restrict__ A,
                                                    const unsigned short* __restrict__ Bt,
                                                    void* __restrict__ C,
                                                    int M, int N, int K,
                                                    int ldc,
                                                    int cMode, const int* __restrict__ flagp,
                                                    unsigned short* __restrict__ vTout) {
    const int f = *flagp;
    __shared__ __align__(16) unsigned char smem[32768];
    unsigned short* As = (unsigned short*)smem;      // [2][128][32] bf16 16 KB
    unsigned short* Bsu = As + 8192;                 // [2][128][32] bf16 16 KB
    f32x4* scr4 = (f32x4*)smem;                      // merge scratch (32 KB)

    const int tid = threadIdx.x;
    const int wave = tid >> 6, lane = tid & 63;
    const int kgrp = wave >> 2;          // 0 or 1: K-half
    const int w4 = wave & 3;             // spatial wave id within group
    const int lin = blockIdx.y * gridDim.x + blockIdx.x;
    const int nwg = gridDim.x * gridDim.y;
    const int swz = (lin & 7) * (nwg >> 3) + (lin >> 3);
    const int row0 = (swz / gridDim.x) * 128, col0 = (swz % gridDim.x) * 128;
    const int wrow = (w4 >> 1) * 64, wcol = (w4 & 1) * 64;
    const int mlane = lane & 15, quad = lane >> 4;
    const int kHalf = K >> 1;

    const unsigned short* Ab = A + (size_t)row0 * K + (size_t)kgrp * kHalf;
    const unsigned short* Bb = Bt + (size_t)col0 * K + (size_t)kgrp * kHalf;
    const int t256 = tid & 255;
    const int r0 = t256 >> 2;
    const int kc = (t256 & 3) * 8;
    const size_t off0 = (size_t)r0 * K + kc;
    const size_t off1 = (size_t)(r0 + 64) * K + kc;
    char* AsW = (char*)As + kgrp * 8192 + w4 * 1024;
    char* BsW = (char*)Bsu + kgrp * 8192 + w4 * 1024;
    const int ldsBase = kgrp * 4096;

    f32x4 acc[4][4] = {};

    for (int k0 = 0; k0 < kHalf; k0 += 32) {
        GLL16(Ab + off0 + k0, AsW);
        GLL16(Ab + off1 + k0, AsW + 4096);
        GLL16(Bb + off0 + k0, BsW);
        GLL16(Bb + off1 + k0, BsW + 4096);
        __syncthreads();
        bf16x8 a[4], b[4];
#pragma unroll
        for (int i = 0; i < 4; i++)
            a[i] = *(const bf16x8*)&As[ldsBase + (wrow + i * 16 + mlane) * 32 + quad * 8];
#pragma unroll
        for (int j = 0; j < 4; j++)
            b[j] = *(const bf16x8*)&Bsu[ldsBase + (wcol + j * 16 + mlane) * 32 + quad * 8];
#pragma unroll
        for (int i = 0; i < 4; i++)
#pragma unroll
            for (int j = 0; j < 4; j++)
                acc[i][j] = __builtin_amdgcn_mfma_f32_16x16x32_bf16(a[i], b[j], acc[i][j], 0, 0, 0);
        __syncthreads();
    }

    // --- accumulator merge: waves 4..7 hand their acc to waves 0..3 ---
    {
        const int col = (wave & 1) * 64 + lane;
        if (kgrp == 1 && w4 < 2) {
#pragma unroll
            for (int i = 0; i < 4; i++)
#pragma unroll
                for (int j = 0; j < 4; j++)
                    scr4[(i * 4 + j) * 128 + col] = acc[i][j];
        }
        __syncthreads();
        if (kgrp == 0 && w4 < 2) {
#pragma unroll
            for (int i = 0; i < 4; i++)
#pragma unroll
                for (int j = 0; j < 4; j++)
                    acc[i][j] += scr4[(i * 4 + j) * 128 + col];
        }
        __syncthreads();
        if (kgrp == 1 && w4 >= 2) {
#pragma unroll
            for (int i = 0; i < 4; i++)
#pragma unroll
                for (int j = 0; j < 4; j++)
                    scr4[(i * 4 + j) * 128 + col] = acc[i][j];
        }
        __syncthreads();
        if (kgrp == 0 && w4 >= 2) {
#pragma unroll
            for (int i = 0; i < 4; i++)
#pragma unroll
                for (int j = 0; j < 4; j++)
                    acc[i][j] += scr4[(i * 4 + j) * 128 + col];
        }
    }
    if (kgrp != 0) return;

    // --- epilogue routing ---
    float* Cf = nullptr;
    unsigned short* Cb16 = nullptr;
    bool doT = false;
    int tOff = 0;
    if (cMode == 0) Cf = (float*)C;
    else if (cMode == 1) Cb16 = (unsigned short*)C;
    else if (cMode == 2) { if (f) Cf = (float*)C; else Cb16 = (unsigned short*)C; }
    else if (cMode == 4) {
        if (col0 < NQK) Cf = (float*)C;
        else { doT = true; tOff = NQK; }
    }
    if (cMode <= 3 && vTout) doT = true;

#pragma unroll
    for (int i = 0; i < 4; i++)
#pragma unroll
        for (int j = 0; j < 4; j++) {
            const int col = col0 + wcol + j * 16 + mlane;
            if (Cf) {
#pragma unroll
                for (int r = 0; r < 4; r++) {
                    const int row = row0 + wrow + i * 16 + quad * 4 + r;
                    Cf[(size_t)row * ldc + col] = acc[i][j][r];
                }
            } else if (Cb16) {
#pragma unroll
                for (int r = 0; r < 4; r++) {
                    const int row = row0 + wrow + i * 16 + quad * 4 + r;
                    Cb16[(size_t)row * ldc + col] = f2bf(acc[i][j][r]);
                }
            }
            if (doT) {
                ushort4 pk;
                pk.x = f2bf(acc[i][j][0]); pk.y = f2bf(acc[i][j][1]);
                pk.z = f2bf(acc[i][j][2]); pk.w = f2bf(acc[i][j][3]);
                *(ushort4*)(vTout + (size_t)(col - tOff) * M + row0 + wrow + i * 16 + quad * 4) = pk;
            }
        }
}

// ---------------------------------------------------------------------------
// Fused LayerNorm: reads fused qk (4096 x 384), writes qpre/kpre (4096 x 192).
// ---------------------------------------------------------------------------
__global__ __launch_bounds__(192) void ln_kernel(const float* __restrict__ qk,
                                                 float* __restrict__ q, float* __restrict__ k,
                                                 const void* __restrict__ gq,
                                                 const void* __restrict__ bq,
                                                 const void* __restrict__ gk,
                                                 const void* __restrict__ bk,
                                                 const int* __restrict__ flagp) {
    const int f = *flagp;
    const int row = blockIdx.x, t = threadIdx.x;
    float vq = qk[(size_t)row * NQK + t];
    float vk = qk[(size_t)row * NQK + HFD + t];
    float s[4] = {vq, vq * vq, vk, vk * vk};
    __shared__ float part[4][3];
    const int w = t >> 6, lane = t & 63;
#pragma unroll
    for (int i = 0; i < 4; i++) {
        float v = s[i];
        for (int off = 32; off; off >>= 1) v += __shfl_down(v, off);
        if (lane == 0) part[i][w] = v;
    }
    __syncthreads();
    float sq  = part[0][0] + part[0][1] + part[0][2];
    float sq2 = part[1][0] + part[1][1] + part[1][2];
    float sk  = part[2][0] + part[2][1] + part[2][2];
    float sk2 = part[3][0] + part[3][1] + part[3][2];
    const float inv = 1.0f / (float)HFD;
    float muq = sq * inv, muk = sk * inv;
    float varq = sq2 * inv - muq * muq;
    float vark = sk2 * inv - muk * muk;
    float oq = (vq - muq) * rsqrtf(varq + 1e-5f) * ldin(gq, t, f) + ldin(bq, t, f);
    float ok = (vk - muk) * rsqrtf(vark + 1e-5f) * ldin(gk, t, f) + ldin(bk, t, f);
    q[(size_t)row * HFD + t] = oq;
    k[(size_t)row * HFD + t] = ok;
}

// ---------------------------------------------------------------------------
// Fused chunk-state + exclusive prefix + z prefix, MFMA.
// 1-D grid 768, XCD-chunk-swizzled.
// ---------------------------------------------------------------------------
__global__ __launch_bounds__(256) void state_prefix_mfma(const float* __restrict__ kn,
                                                         const unsigned short* __restrict__ vT,
                                                         unsigned short* __restrict__ St,
                                                         float* __restrict__ zc) {
    const int lin = blockIdx.x;
    const int swz = (lin & 7) * 96 + (lin >> 3);   // 768 % 8 == 0, bijective
    const int bx = swz & 15;            // d2 tile = i index
    const int by = (swz >> 4) & 1;      // dv half
    const int bh = swz >> 5;
    const int h = bh % Hc, b = bh / Hc;
    const int t0 = bx * 16;
    const int tid = threadIdx.x;
    const int wave = tid >> 6, lane = tid & 63;
    const int mlane = lane & 15, quad = lane >> 4;

    __shared__ __align__(16) float kcs[CHK * FDc];          // [c][16] f32, 8 KB
    __shared__ __align__(16) unsigned short K2t[16 * 136];  // [d2l][c pad]  4.25 KB
    __shared__ __align__(16) unsigned short Vs[64 * 136];   // [dvL][c pad] 17 KB
    __shared__ float zp[16][17];
    __shared__ float zpre[16];
    if (tid < 16) zpre[tid] = 0.f;

    f32x4 acc = {};
    const int kr = tid >> 1, khf = tid & 1;
    const int d2l = tid & 15, cg = tid >> 4;
    const int vrow = tid >> 2, vseg = tid & 3;
    const int dvL = wave * 16 + mlane;

    for (int n = 0; n < NCH; n++) {
        const int row0 = b * Lc + n * CHK;
        __syncthreads();
        {
            const float4* src = (const float4*)(kn + (size_t)(row0 + kr) * HFD + h * FDc + khf * 8);
            *(float4*)(kcs + kr * 16 + khf * 8)     = src[0];
            *(float4*)(kcs + kr * 16 + khf * 8 + 4) = src[1];
            const uint4* g = (const uint4*)(vT + (size_t)(h * 128 + by * 64 + vrow) * ROWS + row0 + vseg * 32);
            *(uint4*)(Vs + vrow * 136 + vseg * 32)      = g[0];
            *(uint4*)(Vs + vrow * 136 + vseg * 32 + 8)  = g[1];
            *(uint4*)(Vs + vrow * 136 + vseg * 32 + 16) = g[2];
            *(uint4*)(Vs + vrow * 136 + vseg * 32 + 24) = g[3];
        }
        __syncthreads();
        {
            float zs_ = 0.f;
            unsigned short pk[8];
#pragma unroll
            for (int u = 0; u < 8; u++) {
                int c = cg * 8 + u;
                float p = kcs[c * 16 + bx] * kcs[c * 16 + d2l] * 0.25f;
                zs_ += p;
                pk[u] = f2bf(p);
            }
            uint4 w;
            w.x = pack2(pk[0], pk[1]); w.y = pack2(pk[2], pk[3]);
            w.z = pack2(pk[4], pk[5]); w.w = pack2(pk[6], pk[7]);
            *(uint4*)(K2t + d2l * 136 + cg * 8) = w;
            zp[d2l][cg] = zs_;
        }
        __syncthreads();
        {
            size_t base = (((size_t)(bh * NCH + n) * 16 + bx) * 128) * 16;
            int dv = by * 64 + dvL;
            ushort4 pk;
            pk.x = f2bf(acc[0]); pk.y = f2bf(acc[1]);
            pk.z = f2bf(acc[2]); pk.w = f2bf(acc[3]);
            *(ushort4*)(St + base + (size_t)dv * 16 + quad * 4) = pk;
            if (tid < 16) {
                float s = 0.f;
#pragma unroll
                for (int c = 0; c < 16; c++) s += zp[tid][c];
                if (by == 0)
                    zc[(size_t)(bh * NCH + n) * D2c + t0 + tid] = zpre[tid];
                zpre[tid] += s;
            }
        }
        {
#pragma unroll
            for (int ks = 0; ks < 4; ks++) {
                bf16x8 a = *(const bf16x8*)(K2t + mlane * 136 + ks * 32 + quad * 8);
                bf16x8 bfr = *(const bf16x8*)(Vs + dvL * 136 + ks * 32 + quad * 8);
                acc = __builtin_amdgcn_mfma_f32_16x16x32_bf16(a, bfr, acc, 0, 0, 0);
            }
        }
    }
}

// ---------------------------------------------------------------------------
// MFMA chunk output. Per (bh, n) block (XCD-chunk-swizzled):
//   num1 = Q2 @ S_prefix (St bf16, tile-major layout), den1 = Q2 . z (fused)
//   P    = Q @ K^T (zero-padded K=32 MFMA), A = tril(P^2/16) -> LDS bf16
//   num2 = A @ V (via vT bf16 [dv][seq]),   den2 = rowsum(A)
//   o    = (num1+num2) / (den1+den2+eps)  -> bf16 row-major [4096][1536]
// ---------------------------------------------------------------------------
__global__ __launch_bounds__(256) void chunk_out_mfma(const float* __restrict__ qn,
                                                      const float* __restrict__ kn,
                                                      const unsigned short* __restrict__ St,
                                                      const float* __restrict__ z,
                                                      const unsigned short* __restrict__ vT,
                                                      unsigned short* __restrict__ o) {
    const int lin = blockIdx.x;
    const int blk = (lin & 7) * 48 + (lin >> 3);   // 384 % 8 == 0, bijective
    const int n = blk & 15, bh = blk >> 4;
    const int h = bh % Hc, b = bh / Hc;
    const int row0 = b * Lc + n * CHK;
    const int tid = threadIdx.x;
    const int wave = tid >> 6, lane = tid & 63;
    const int mlane = lane & 15, quad = lane >> 4;
    const int wrow = (wave >> 1) * 64, wcol = (wave & 1) * 64;

    __shared__ __align__(16) unsigned char lds[61952];
    float* Qs   = (float*)lds;                           // [128][16] f32   8192
    float* zs   = (float*)(lds + 8192);                  // [256]           1024
    float* denp = (float*)(lds + 9216);                  // [2][128]        1024
    float* dinv = (float*)(lds + 10240);                 // [128]           512
    unsigned char* U = lds + 10752;
    unsigned short* Q2s = (unsigned short*)U;            // [128][40] bf16  10240
    unsigned short* Sts = (unsigned short*)(U + 10240);  // [128][40] bf16  10240
    unsigned short* Kb  = (unsigned short*)U;            // [128][32] bf16  8192
    unsigned short* Qb  = (unsigned short*)(U + 8192);   // [128][32] bf16  8192
    unsigned short* At  = (unsigned short*)(U + 16384);  // [128][136] bf16 34816
    unsigned short* Vs  = (unsigned short*)U;            // [128][40] bf16  10240

    // ---- load Qs (f32, full 16 floats per row) and zs ----
    {
        int r = tid >> 1, hf = tid & 1;
        const float4* src = (const float4*)(qn + (size_t)(row0 + r) * HFD + h * FDc + hf * 8);
        *(float4*)(Qs + r * 16 + hf * 8)     = src[0];
        *(float4*)(Qs + r * 16 + hf * 8 + 4) = src[1];
        if (tid < 64)
            ((float4*)zs)[tid] = ((const float4*)(z + ((size_t)bh * NCH + n) * D2c))[tid];
    }
    __syncthreads();

    const int qc = tid >> 1, qhalf = tid & 1;
    float qr[16];
#pragma unroll
    for (int ff = 0; ff < 16; ff++) qr[ff] = Qs[qc * 16 + ff];

    f32x4 acc[4][4] = {};
    float den1 = 0.f;
    const unsigned short* Stb = St + ((size_t)bh * NCH + n) * ((size_t)D2c * DVc);

    // ---- num1: K = 256 over d2 in 32-slabs ----
    for (int k0 = 0; k0 < 256; k0 += 32) {
        {
            unsigned short pk[16];
#pragma unroll
            for (int kk = 0; kk < 16; kk++) {
                int d2 = k0 + qhalf * 16 + kk;
                float val = qr[d2 >> 4] * qr[d2 & 15] * 0.25f;
                den1 += val * zs[d2];
                pk[kk] = f2bf(val);
            }
            uint4 w0, w1;
            w0.x = pack2(pk[0], pk[1]);  w0.y = pack2(pk[2], pk[3]);
            w0.z = pack2(pk[4], pk[5]);  w0.w = pack2(pk[6], pk[7]);
            w1.x = pack2(pk[8], pk[9]);  w1.y = pack2(pk[10], pk[11]);
            w1.z = pack2(pk[12], pk[13]); w1.w = pack2(pk[14], pk[15]);
            *(uint4*)(Q2s + qc * 40 + qhalf * 16) = w0;
            *(uint4*)(Q2s + qc * 40 + qhalf * 16 + 8) = w1;
        }
        {
            // St tile-major: element (dv=r, d2=k0+hf*16+s) at (k0/16+hf)*2048 + r*16 + s
            int r = tid >> 1, hf = tid & 1;
            const uint4* g = (const uint4*)(Stb + (size_t)((k0 >> 4) + hf) * 2048 + r * 16);
            uint4 d0 = g[0], d1 = g[1];
            *(uint4*)(Sts + r * 40 + hf * 16) = d0;
            *(uint4*)(Sts + r * 40 + hf * 16 + 8) = d1;
        }
        __syncthreads();
        bf16x8 a[4], bfr[4];
#pragma unroll
        for (int i = 0; i < 4; i++)
            a[i] = *(const bf16x8*)(Q2s + (wrow + i * 16 + mlane) * 40 + quad * 8);
#pragma unroll
        for (int j = 0; j < 4; j++)
            bfr[j] = *(const bf16x8*)(Sts + (wcol + j * 16 + mlane) * 40 + quad * 8);
#pragma unroll
        for (int i = 0; i < 4; i++)
#pragma unroll
            for (int j = 0; j < 4; j++)
                acc[i][j] = __builtin_amdgcn_mfma_f32_16x16x32_bf16(a[i], bfr[j], acc[i][j], 0, 0, 0);
        __syncthreads();
    }
    denp[qhalf * 128 + qc] = den1;

    // ---- build Qb, Kb zero-padded [128][32] ----
    {
        int r = tid >> 1, hf = tid & 1;
        if (hf == 0) {
            unsigned short pq[16], pkk[16];
#pragma unroll
            for (int ff = 0; ff < 16; ff++) pq[ff] = f2bf(Qs[r * 16 + ff]);
            const float* kg = kn + (size_t)(row0 + r) * HFD + h * FDc;
#pragma unroll
            for (int ff = 0; ff < 16; ff++) pkk[ff] = f2bf(kg[ff]);
            uint4 w;
            w.x = pack2(pq[0], pq[1]);  w.y = pack2(pq[2], pq[3]);
            w.z = pack2(pq[4], pq[5]);  w.w = pack2(pq[6], pq[7]);
            *(uint4*)(Qb + r * 32) = w;
            w.x = pack2(pq[8], pq[9]);  w.y = pack2(pq[10], pq[11]);
            w.z = pack2(pq[12], pq[13]); w.w = pack2(pq[14], pq[15]);
            *(uint4*)(Qb + r * 32 + 8) = w;
            w.x = pack2(pkk[0], pkk[1]);  w.y = pack2(pkk[2], pkk[3]);
            w.z = pack2(pkk[4], pkk[5]);  w.w = pack2(pkk[6], pkk[7]);
            *(uint4*)(Kb + r * 32) = w;
            w.x = pack2(pkk[8], pkk[9]);  w.y = pack2(pkk[10], pkk[11]);
            w.z = pack2(pkk[12], pkk[13]); w.w = pack2(pkk[14], pkk[15]);
            *(uint4*)(Kb + r * 32 + 8) = w;
        } else {
            uint4 zz = make_uint4(0, 0, 0, 0);
            *(uint4*)(Qb + r * 32 + 16) = zz;
            *(uint4*)(Qb + r * 32 + 24) = zz;
            *(uint4*)(Kb + r * 32 + 16) = zz;
            *(uint4*)(Kb + r * 32 + 24) = zz;
        }
    }
    __syncthreads();

    // ---- P = Q @ K^T, A = tril(P^2/16) ----
    {
        f32x4 pacc[4][4] = {};
        bf16x8 a[4], bfr[4];
#pragma unroll
        for (int i = 0; i < 4; i++)
            a[i] = *(const bf16x8*)(Qb + (wrow + i * 16 + mlane) * 32 + quad * 8);
#pragma unroll
        for (int j = 0; j < 4; j++)
            bfr[j] = *(const bf16x8*)(Kb + (wcol + j * 16 + mlane) * 32 + quad * 8);
#pragma unroll
        for (int i = 0; i < 4; i++)
#pragma unroll
            for (int j = 0; j < 4; j++)
                pacc[i][j] = __builtin_amdgcn_mfma_f32_16x16x32_bf16(a[i], bfr[j], pacc[i][j], 0, 0, 0);
#pragma unroll
        for (int i = 0; i < 4; i++)
#pragma unroll
            for (int j = 0; j < 4; j++) {
                int e = wcol + j * 16 + mlane;
#pragma unroll
                for (int r = 0; r < 4; r++) {
                    int c = wrow + i * 16 + quad * 4 + r;
                    float p = pacc[i][j][r];
                    float aval = (e <= c) ? p * p * 0.0625f : 0.f;
                    At[c * 136 + e] = f2bf(aval);
                }
            }
    }
    __syncthreads();

    // ---- dinv[c] = 1/(den1 + rowsum(A) + eps) ----
    if (tid < 128) {
        float rs = 0.f;
#pragma unroll
        for (int e8 = 0; e8 < 128; e8 += 8) {
            bf16x8 v8 = *(const bf16x8*)(At + tid * 136 + e8);
#pragma unroll
            for (int u = 0; u < 8; u++) rs += (float)v8[u];
        }
        dinv[tid] = 1.0f / (denp[tid] + denp[128 + tid] + rs + 1e-12f);
    }

    // ---- num2: A @ V, K = 128 over e in 32-slabs ----
    for (int e0 = 0; e0 < 128; e0 += 32) {
        {
            int r = tid >> 1, hf = tid & 1;
            const uint4* g = (const uint4*)(vT + (size_t)(h * 128 + r) * ROWS + row0 + e0 + hf * 16);
            uint4 d0 = g[0], d1 = g[1];
            *(uint4*)(Vs + r * 40 + hf * 16) = d0;
            *(uint4*)(Vs + r * 40 + hf * 16 + 8) = d1;
        }
        __syncthreads();
        bf16x8 a[4], bfr[4];
#pragma unroll
        for (int i = 0; i < 4; i++)
            a[i] = *(const bf16x8*)(At + (wrow + i * 16 + mlane) * 136 + e0 + quad * 8);
#pragma unroll
        for (int j = 0; j < 4; j++)
            bfr[j] = *(const bf16x8*)(Vs + (wcol + j * 16 + mlane) * 40 + quad * 8);
#pragma unroll
        for (int i = 0; i < 4; i++)
#pragma unroll
            for (int j = 0; j < 4; j++)
                acc[i][j] = __builtin_amdgcn_mfma_f32_16x16x32_bf16(a[i], bfr[j], acc[i][j], 0, 0, 0);
        __syncthreads();
    }

    // ---- epilogue ----
#pragma unroll
    for (int i = 0; i < 4; i++)
#pragma unroll
        for (int j = 0; j < 4; j++) {
            int col = h * 128 + wcol + j * 16 + mlane;
#pragma unroll
            for (int r = 0; r < 4; r++) {
                int c = wrow + i * 16 + quad * 4 + r;
                o[(size_t)(row0 + c) * HDV + col] = f2bf(acc[i][j][r] * dinv[c]);
            }
        }
}

// ---------------------------------------------------------------------------
extern "C" void kernel_launch(void* const* d_in, const int* in_sizes, int n_in,
                              void* d_out, int out_size, void* d_ws, size_t ws_size,
                              hipStream_t stream) {
    const void* hs = d_in[0];
    const void* Wq = d_in[1];
    const void* Wk = d_in[2];
    const void* Wv = d_in[3];
    const void* Wo = d_in[4];
    const void* gq = d_in[5];
    const void* bq = d_in[6];
    const void* gk = d_in[7];
    const void* bk = d_in[8];

    int* flag = (int*)d_ws;
    float* base = (float*)d_ws + 16;
    float* qpre = base;                                   // 4096*192 f32
    float* kpre = qpre + (size_t)ROWS * HFD;              // 4096*192 f32
    float* vreg = kpre + (size_t)ROWS * HFD;              // 25.2 MB region (St lives here)
    float* Sc   = vreg + (size_t)ROWS * HDV;              // 50 MB region (qk/Wqkvt aliases)
    float* zc   = Sc + (size_t)Bc * Hc * NCH * D2c * DVc; // 384*256 f32
    float* fend = zc + (size_t)Bc * Hc * NCH * D2c;
    unsigned short* hsb = (unsigned short*)fend;          // 4096*1536 bf16
    unsigned short* ob  = hsb;                            // alias (hsb dead before ob)
    unsigned short* Wot = hsb + (size_t)ROWS * DMc;       // 1536*1536 bf16
    unsigned short* vT  = Wot + (size_t)HDV * DMc;        // 1536*4096 bf16 (12.6 MB)
    // aliases into Sc region:
    float* qk = Sc;                                       // 4096*384 f32 (dead after ln)
    unsigned short* Wqkvt = (unsigned short*)(Sc + (size_t)ROWS * NQK);  // 1920*1536 bf16 (dead after proj)
    // St (bf16 exclusive-prefix state, tile-major) uses the old v region.
    unsigned short* St = (unsigned short*)vreg;           // 24*16*16*128*16 bf16 = 25.2 MB

    probe_dtype<<<1, 256, 0, stream>>>((const unsigned short*)hs, flag);

    // fused bf16 prep: weight transposes + hs conversion in one launch
    prep_all<<<1296 + ROWS * DMc / 1024, 256, 0, stream>>>(
        hs, Wq, Wk, Wv, Wo, hsb, Wqkvt, Wot, flag);

    // fused projection: [qk | v] = hs @ [Wq|Wk|Wv]; qk cols -> f32 (ldc=NQK),
    // v cols -> vT bf16 transposed. 480 blocks x 8 waves, split-K, XCD-swizzled.
    gemm_mfma_bt<<<dim3(NPRJ / 128, ROWS / 128), 512, 0, stream>>>(
        hsb, Wqkvt, qk, ROWS, NPRJ, DMc, NQK, 4, flag, vT);

    ln_kernel<<<ROWS, HFD, 0, stream>>>(qk, qpre, kpre, gq, bq, gk, bk, flag);

    // fused state + prefix (1-D grid, XCD-chunk-swizzled)
    state_prefix_mfma<<<16 * 2 * Bc * Hc, 256, 0, stream>>>(kpre, vT, St, zc);

    // chunk output (4-wave, XCD-chunk-swizzled)
    chunk_out_mfma<<<Bc * Hc * NCH, 256, 0, stream>>>(qpre, kpre, St, zc, vT, ob);

    // out = o @ Wo, direct write (384 blocks x 8 waves, split-K, XCD-swizzled)
    gemm_mfma_bt<<<dim3(DMc / 128, ROWS / 128), 512, 0, stream>>>(
        ob, Wot, d_out, ROWS, DMc, HDV, DMc, 2, flag, nullptr);
}